// Round 1
// baseline (223.825 us; speedup 1.0000x reference)
//
#include <hip/hip_runtime.h>
#include <hip/hip_bf16.h>

// Problem constants (from reference): B=64, I=64, O=64, G=4096, X=4, RHO=1
#define BB 64
#define II 64
#define OO 64
#define GG 4096

constexpr int GS   = 32;          // g sub-chunk staged in LDS per step
constexpr int ROWF = GS * 4 + 4;  // padded LDS row per o (floats): 132 -> odd 16B-unit stride

// ---------------------------------------------------------------------------
// Kernel 1: main contraction. Block = (i, g-chunk). Per-block output tile is
// the full 64b x 64o x 4x partial sum over its g-chunk. Per-thread tile:
// 4b x 4o x 4x = 64 f32 accumulators. rbf and weights staged in LDS.
// Weights LDS layout keeps global order [o][g'][x] (direct float4 copy, no
// transpose) with +4-float row pad; the o-tile per thread is strided by 16
// so the 16 distinct o-row addresses per wave hit all 8 bank-quads (~2-way).
// ---------------------------------------------------------------------------
__global__ __launch_bounds__(256, 2)
void kan_main(const float* __restrict__ xg, const float* __restrict__ grd,
              const float* __restrict__ wts, float* __restrict__ dst,
              int nch, int atomic_mode)
{
    __shared__ __align__(16) float rbf_s[GS][BB];     // 8 KB
    __shared__ __align__(16) float w_s[OO * ROWF];    // 33 KB

    const int i    = blockIdx.x;
    const int ch   = blockIdx.y;
    const int gc   = GG / nch;
    const int g0   = ch * gc;
    const int nsub = gc / GS;

    const int tid = threadIdx.x;
    const int og  = tid & 15;    // o = og + 16k, k=0..3
    const int bg  = tid >> 4;    // b = 4*bg + j, j=0..3
    const int b0  = bg * 4;

    // rbf staging map: one b per lane-group, 4 g at a time
    const int sbb = tid & 63;
    const int sgq = tid >> 6;
    const float4 xv = *reinterpret_cast<const float4*>(&xg[(sbb * II + i) * 4]);

    // weights as float4: index (o*G + g) within slice i
    const float4* wg = reinterpret_cast<const float4*>(wts) + (size_t)(i * OO) * GG;

    float acc[4][4][4];
    #pragma unroll
    for (int k = 0; k < 4; ++k)
        #pragma unroll
        for (int j = 0; j < 4; ++j)
            #pragma unroll
            for (int c = 0; c < 4; ++c) acc[k][j][c] = 0.f;

    // prologue: prefetch chunk 0 weights into registers
    float4 pre[8];
    #pragma unroll
    for (int it = 0; it < 8; ++it) {
        const int f = tid + 256 * it;
        pre[it] = wg[(size_t)(f >> 5) * GG + (g0 + (f & 31))];
    }

    for (int s = 0; s < nsub; ++s) {
        const int gs0 = g0 + s * GS;
        __syncthreads();                       // LDS free (prev compute done)

        // write prefetched weights to LDS (float4, coalesced, conflict-free)
        #pragma unroll
        for (int it = 0; it < 8; ++it) {
            const int f = tid + 256 * it;
            *reinterpret_cast<float4*>(&w_s[(f >> 5) * ROWF + (f & 31) * 4]) = pre[it];
        }
        // rbf for this chunk
        #pragma unroll
        for (int q = 0; q < GS / 4; ++q) {
            const int gg = sgq + q * 4;
            const float4 gv = *reinterpret_cast<const float4*>(&grd[(gs0 + gg) * 4]);
            const float d0 = xv.x - gv.x, d1 = xv.y - gv.y,
                        d2 = xv.z - gv.z, d3 = xv.w - gv.w;
            rbf_s[gg][sbb] = __expf(-(d0 * d0 + d1 * d1 + d2 * d2 + d3 * d3));
        }
        __syncthreads();

        // prefetch next chunk (hides HBM latency under the FMA phase)
        if (s + 1 < nsub) {
            #pragma unroll
            for (int it = 0; it < 8; ++it) {
                const int f = tid + 256 * it;
                pre[it] = wg[(size_t)(f >> 5) * GG + (gs0 + GS + (f & 31))];
            }
        }

        // compute: per g': 1 b128 (rbf) + 4 b128 (w) + 64 FMA
        #pragma unroll 4
        for (int gg = 0; gg < GS; ++gg) {
            const float4 rb = *reinterpret_cast<const float4*>(&rbf_s[gg][b0]);
            const float rbv[4] = {rb.x, rb.y, rb.z, rb.w};
            #pragma unroll
            for (int k = 0; k < 4; ++k) {
                const float4 wv4 = *reinterpret_cast<const float4*>(
                    &w_s[(og + 16 * k) * ROWF + gg * 4]);
                const float wv[4] = {wv4.x, wv4.y, wv4.z, wv4.w};
                #pragma unroll
                for (int j = 0; j < 4; ++j) {
                    acc[k][j][0] += rbv[j] * wv[0];
                    acc[k][j][1] += rbv[j] * wv[1];
                    acc[k][j][2] += rbv[j] * wv[2];
                    acc[k][j][3] += rbv[j] * wv[3];
                }
            }
        }
    }

    // epilogue
    if (!atomic_mode) {
        float* pp = dst + (size_t)(ch * gridDim.x + i) * (BB * OO * 4);
        #pragma unroll
        for (int k = 0; k < 4; ++k)
            #pragma unroll
            for (int j = 0; j < 4; ++j) {
                const float4 v = make_float4(acc[k][j][0], acc[k][j][1],
                                             acc[k][j][2], acc[k][j][3]);
                *reinterpret_cast<float4*>(
                    &pp[(((b0 + j) * OO) + (og + 16 * k)) * 4]) = v;
            }
    } else {
        #pragma unroll
        for (int k = 0; k < 4; ++k)
            #pragma unroll
            for (int j = 0; j < 4; ++j)
                #pragma unroll
                for (int c = 0; c < 4; ++c)
                    atomicAdd(&dst[(((b0 + j) * OO) + (og + 16 * k)) * 4 + c],
                              acc[k][j][c]);
    }
}

// ---------------------------------------------------------------------------
// Kernel 2: tree-reduce P partials -> 4 slices (keeps >=256 blocks pulling HBM)
// ---------------------------------------------------------------------------
__global__ void kan_reduce(const float* __restrict__ part,
                           float* __restrict__ part2, int Q)
{
    const int idx = blockIdx.x * 256 + threadIdx.x;  // [0, 16384)
    const int pg  = blockIdx.y;                      // [0, 4)
    const float* p = part + (size_t)pg * Q * 16384 + idx;
    float s = 0.f;
    for (int q = 0; q < Q; ++q) s += p[(size_t)q * 16384];
    part2[pg * 16384 + idx] = s;
}

// ---------------------------------------------------------------------------
// Kernel 3: final 4-way sum + SiLU/Cayley branch + bias.
// Cl(2,0) Cayley: nonzeros at (x, y=x^z) with sign flips:
//  z=0: +,+,+,- ; z=1: +,+,-,+ ; z=2: +,+,+,- ; z=3: +,+,-,+
// Each thread owns one (b,o) and computes all 4 z -> fully static indexing.
// ---------------------------------------------------------------------------
__global__ void kan_out(const float* __restrict__ part2,
                        const float* __restrict__ xg,
                        const float* __restrict__ sw,
                        const float* __restrict__ sb,
                        float* __restrict__ out, int R)
{
    const int t = blockIdx.x * 256 + threadIdx.x;    // [0, 4096) over (b,o)
    const int b = t >> 6, o = t & 63;

    float o0, o1, o2, o3;
    if (R > 0) {
        o0 = o1 = o2 = o3 = 0.f;
        const float4* p2 = reinterpret_cast<const float4*>(part2);
        for (int r = 0; r < R; ++r) {
            const float4 v = p2[(size_t)r * 4096 + t];
            o0 += v.x; o1 += v.y; o2 += v.z; o3 += v.w;
        }
    } else {  // atomic fallback: main sums already in out
        const float4 v = reinterpret_cast<const float4*>(out)[t];
        o0 = v.x; o1 = v.y; o2 = v.z; o3 = v.w;
    }

    const float4* xg4 = reinterpret_cast<const float4*>(xg);
    const float4* sw4 = reinterpret_cast<const float4*>(sw);
    const float4* sb4 = reinterpret_cast<const float4*>(sb);
    #pragma unroll 4
    for (int i = 0; i < II; ++i) {
        const float4 xvv = xg4[b * II + i];
        const float4 swv = sw4[i * OO + o];
        const float4 sbv = sb4[i * OO + o];
        const float s0 = xvv.x / (1.f + __expf(-xvv.x));
        const float s1 = xvv.y / (1.f + __expf(-xvv.y));
        const float s2 = xvv.z / (1.f + __expf(-xvv.z));
        const float s3 = xvv.w / (1.f + __expf(-xvv.w));
        o0 += swv.x * s0 + swv.y * s1 + swv.z * s2 - swv.w * s3 + sbv.x;
        o1 += swv.x * s1 + swv.y * s0 - swv.z * s3 + swv.w * s2 + sbv.y;
        o2 += swv.x * s2 + swv.y * s3 + swv.z * s0 - swv.w * s1 + sbv.z;
        o3 += swv.x * s3 + swv.y * s2 - swv.z * s1 + swv.w * s0 + sbv.w;
    }
    reinterpret_cast<float4*>(out)[t] = make_float4(o0, o1, o2, o3);
}

// ---------------------------------------------------------------------------
extern "C" void kernel_launch(void* const* d_in, const int* in_sizes, int n_in,
                              void* d_out, int out_size, void* d_ws, size_t ws_size,
                              hipStream_t stream)
{
    const float* x   = (const float*)d_in[0];
    const float* grd = (const float*)d_in[1];
    const float* w   = (const float*)d_in[2];
    const float* sw  = (const float*)d_in[3];
    const float* sb  = (const float*)d_in[4];
    float* out = (float*)d_out;
    float* ws  = (float*)d_ws;

    // workspace need: P=64*nch partials of 16384 f32 + 4 slices of 16384 f32
    int nch = 8;
    auto need = [](int n) -> size_t { return ((size_t)64 * n + 4) * 16384 * 4; };
    while (nch > 1 && ws_size < need(nch)) nch >>= 1;

    if (ws_size >= need(nch)) {
        const int P = 64 * nch;
        float* part2 = ws + (size_t)P * 16384;
        kan_main<<<dim3(64, nch), 256, 0, stream>>>(x, grd, w, ws, nch, 0);
        kan_reduce<<<dim3(64, 4), 256, 0, stream>>>(ws, part2, P / 4);
        kan_out<<<16, 256, 0, stream>>>(part2, x, sw, sb, out, 4);
    } else {
        // tiny-ws fallback: deterministic enough (f32 atomics, huge threshold)
        hipMemsetAsync(d_out, 0, (size_t)out_size * sizeof(float), stream);
        kan_main<<<dim3(64, 8), 256, 0, stream>>>(x, grd, w, out, 8, 1);
        kan_out<<<16, 256, 0, stream>>>(nullptr, x, sw, sb, out, 0);
    }
}

// Round 2
// 110.995 us; speedup vs baseline: 2.0165x; 2.0165x over previous
//
#include <hip/hip_runtime.h>
#include <hip/hip_bf16.h>

// B=64, I=64, O=64, G=4096, X=4, RHO=1
#define BB 64
#define II 64
#define OO 64
#define GG 4096
#define KS 64            // g per K-step
#define NCH 8            // g-chunks (split-K)
#define GC (GG / NCH)    // 512 g per block
#define NSUB (GC / KS)   // 8 steps

typedef short bf16x8 __attribute__((ext_vector_type(8)));
typedef short bf16x4 __attribute__((ext_vector_type(4)));
typedef float f32x4  __attribute__((ext_vector_type(4)));

static __device__ __forceinline__ short f2bf(float f) {
    __hip_bfloat16 h = __float2bfloat16(f);
    return __builtin_bit_cast(short, h);
}

// ---------------------------------------------------------------------------
// Main: bf16 MFMA split-K GEMM.  C[b][(o,x)] += sum_g rbf[b,g] * w[o,g,x]
// Block (i, ch): full 64x256 output partial over 512 g.  8 waves: wave w owns
// n in [32w, 32w+32) (2 n-tiles), all 4 m-tiles.  LDS tiles swizzled
// (byte ^= (row&7)<<4) so ds_read_b128 fragment loads are bank-uniform.
// ---------------------------------------------------------------------------
__global__ __launch_bounds__(512, 4)
void kan_main(const float* __restrict__ xg, const float* __restrict__ grd,
              const float* __restrict__ wts, float* __restrict__ dst,
              int atomic_mode)
{
    __shared__ __align__(16) unsigned short Bs[256 * KS];  // [n][k] bf16, 32 KB
    __shared__ __align__(16) unsigned short As[64 * KS];   // [m][k] bf16,  8 KB
    __shared__ __align__(16) float4 Gs[GC];                // grid slice,   8 KB

    const int i  = blockIdx.x;
    const int ch = blockIdx.y;
    const int g0 = ch * GC;

    const int t    = threadIdx.x;
    const int lane = t & 63;
    const int wv   = t >> 6;

    // grid slice -> LDS (one float4/thread); first __syncthreads covers it
    Gs[t] = reinterpret_cast<const float4*>(grd)[g0 + t];

    // rbf task: thread computes 8 g for one b
    const int am = t >> 3;   // b row
    const int ak = t & 7;    // k-octet
    const float4 xv = reinterpret_cast<const float4*>(xg)[am * II + i];

    // B staging task: gq = g-quad, o in {o0, o0+32}; 4 float4 = 64B contiguous
    const int gq = t & 15;
    const int o0 = t >> 4;   // 0..31
    const float4* wp0 = reinterpret_cast<const float4*>(wts)
                        + (size_t)i * OO * GG + (size_t)o0 * GG + g0 + gq * 4;
    const float4* wp1 = wp0 + (size_t)32 * GG;

    f32x4 acc[4][2];
    #pragma unroll
    for (int mt = 0; mt < 4; ++mt)
        #pragma unroll
        for (int nt = 0; nt < 2; ++nt) acc[mt][nt] = {0.f, 0.f, 0.f, 0.f};

    // prologue: prefetch step-0 weights
    float4 pre0[4], pre1[4];
    #pragma unroll
    for (int q = 0; q < 4; ++q) { pre0[q] = wp0[q]; pre1[q] = wp1[q]; }

    for (int s = 0; s < NSUB; ++s) {
        __syncthreads();   // LDS free (prev MFMA done; also covers Gs init)

        // ---- stage B: convert + transposed (g<->x) swizzled LDS write ----
        #pragma unroll
        for (int j = 0; j < 2; ++j) {
            const float4 a = j ? pre1[0] : pre0[0];
            const float4 b = j ? pre1[1] : pre0[1];
            const float4 c = j ? pre1[2] : pre0[2];
            const float4 d = j ? pre1[3] : pre0[3];
            const int nb = (o0 + 32 * j) * 4;
            #pragma unroll
            for (int x = 0; x < 4; ++x) {
                const int n = nb + x;
                const float fa = x == 0 ? a.x : x == 1 ? a.y : x == 2 ? a.z : a.w;
                const float fb = x == 0 ? b.x : x == 1 ? b.y : x == 2 ? b.z : b.w;
                const float fc = x == 0 ? c.x : x == 1 ? c.y : x == 2 ? c.z : c.w;
                const float fd = x == 0 ? d.x : x == 1 ? d.y : x == 2 ? d.z : d.w;
                bf16x4 v = {f2bf(fa), f2bf(fb), f2bf(fc), f2bf(fd)};
                *reinterpret_cast<bf16x4*>(
                    &Bs[n * KS + ((gq * 4) ^ ((n & 7) << 3))]) = v;
            }
        }

        // ---- stage A: rbf -> bf16, swizzled b128 write ----
        {
            bf16x8 av;
            #pragma unroll
            for (int e = 0; e < 8; ++e) {
                const float4 gv = Gs[s * KS + ak * 8 + e];
                const float d0 = xv.x - gv.x, d1 = xv.y - gv.y,
                            d2 = xv.z - gv.z, d3 = xv.w - gv.w;
                av[e] = f2bf(__expf(-(d0 * d0 + d1 * d1 + d2 * d2 + d3 * d3)));
            }
            *reinterpret_cast<bf16x8*>(
                &As[am * KS + ((ak * 8) ^ ((am & 7) << 3))]) = av;
        }

        __syncthreads();   // LDS ready

        // issue next step's weight loads (in flight during MFMA phase)
        if (s + 1 < NSUB) {
            #pragma unroll
            for (int q = 0; q < 4; ++q) {
                pre0[q] = wp0[(s + 1) * KS + q];
                pre1[q] = wp1[(s + 1) * KS + q];
            }
        }

        // ---- MFMA phase: 2 k-steps x (4m x 2n) ----
        #pragma unroll
        for (int kk = 0; kk < 2; ++kk) {
            const int kb = kk * 32 + ((lane >> 4) << 3);
            bf16x8 af[4], bb[2];
            #pragma unroll
            for (int mt = 0; mt < 4; ++mt) {
                const int r = mt * 16 + (lane & 15);
                af[mt] = *reinterpret_cast<const bf16x8*>(
                    &As[r * KS + (kb ^ ((r & 7) << 3))]);
            }
            #pragma unroll
            for (int nt = 0; nt < 2; ++nt) {
                const int r = wv * 32 + nt * 16 + (lane & 15);
                bb[nt] = *reinterpret_cast<const bf16x8*>(
                    &Bs[r * KS + (kb ^ ((r & 7) << 3))]);
            }
            #pragma unroll
            for (int mt = 0; mt < 4; ++mt)
                #pragma unroll
                for (int nt = 0; nt < 2; ++nt)
                    acc[mt][nt] = __builtin_amdgcn_mfma_f32_16x16x32_bf16(
                        af[mt], bb[nt], acc[mt][nt], 0, 0, 0);
        }
    }

    // ---- epilogue: C/D layout col=lane&15, row=(lane>>4)*4+reg ----
    if (!atomic_mode) {
        float* pp = dst + (size_t)(ch * 64 + i) * (BB * OO * 4);
        #pragma unroll
        for (int mt = 0; mt < 4; ++mt)
            #pragma unroll
            for (int nt = 0; nt < 2; ++nt) {
                const int n  = wv * 32 + nt * 16 + (lane & 15);
                const int mb = mt * 16 + ((lane >> 4) << 2);
                #pragma unroll
                for (int r = 0; r < 4; ++r)
                    pp[(mb + r) * 256 + n] = acc[mt][nt][r];
            }
    } else {
        #pragma unroll
        for (int mt = 0; mt < 4; ++mt)
            #pragma unroll
            for (int nt = 0; nt < 2; ++nt) {
                const int n  = wv * 32 + nt * 16 + (lane & 15);
                const int mb = mt * 16 + ((lane >> 4) << 2);
                #pragma unroll
                for (int r = 0; r < 4; ++r)
                    atomicAdd(&dst[(mb + r) * 256 + n], acc[mt][nt][r]);
            }
    }
}

// ---------------------------------------------------------------------------
// Tree-reduce 512 partials -> 4 slices
// ---------------------------------------------------------------------------
__global__ void kan_reduce(const float* __restrict__ part,
                           float* __restrict__ part2, int Q)
{
    const int idx = blockIdx.x * 256 + threadIdx.x;  // [0, 16384)
    const int pg  = blockIdx.y;                      // [0, 4)
    const float* p = part + (size_t)pg * Q * 16384 + idx;
    float s = 0.f;
    for (int q = 0; q < Q; ++q) s += p[(size_t)q * 16384];
    part2[pg * 16384 + idx] = s;
}

// ---------------------------------------------------------------------------
// Final sum + SiLU/Cayley (Cl(2,0), static signs) + bias
// ---------------------------------------------------------------------------
__global__ void kan_out(const float* __restrict__ part2,
                        const float* __restrict__ xg,
                        const float* __restrict__ sw,
                        const float* __restrict__ sb,
                        float* __restrict__ out, int R)
{
    const int t = blockIdx.x * 256 + threadIdx.x;    // (b,o)
    const int b = t >> 6, o = t & 63;

    float o0, o1, o2, o3;
    if (R > 0) {
        o0 = o1 = o2 = o3 = 0.f;
        const float4* p2 = reinterpret_cast<const float4*>(part2);
        for (int r = 0; r < R; ++r) {
            const float4 v = p2[(size_t)r * 4096 + t];
            o0 += v.x; o1 += v.y; o2 += v.z; o3 += v.w;
        }
    } else {
        const float4 v = reinterpret_cast<const float4*>(out)[t];
        o0 = v.x; o1 = v.y; o2 = v.z; o3 = v.w;
    }

    const float4* xg4 = reinterpret_cast<const float4*>(xg);
    const float4* sw4 = reinterpret_cast<const float4*>(sw);
    const float4* sb4 = reinterpret_cast<const float4*>(sb);
    #pragma unroll 4
    for (int i = 0; i < II; ++i) {
        const float4 xvv = xg4[b * II + i];
        const float4 swv = sw4[i * OO + o];
        const float4 sbv = sb4[i * OO + o];
        const float s0 = xvv.x / (1.f + __expf(-xvv.x));
        const float s1 = xvv.y / (1.f + __expf(-xvv.y));
        const float s2 = xvv.z / (1.f + __expf(-xvv.z));
        const float s3 = xvv.w / (1.f + __expf(-xvv.w));
        o0 += swv.x * s0 + swv.y * s1 + swv.z * s2 - swv.w * s3 + sbv.x;
        o1 += swv.x * s1 + swv.y * s0 - swv.z * s3 + swv.w * s2 + sbv.y;
        o2 += swv.x * s2 + swv.y * s3 + swv.z * s0 - swv.w * s1 + sbv.z;
        o3 += swv.x * s3 + swv.y * s2 - swv.z * s1 + swv.w * s0 + sbv.w;
    }
    reinterpret_cast<float4*>(out)[t] = make_float4(o0, o1, o2, o3);
}

// ---------------------------------------------------------------------------
extern "C" void kernel_launch(void* const* d_in, const int* in_sizes, int n_in,
                              void* d_out, int out_size, void* d_ws, size_t ws_size,
                              hipStream_t stream)
{
    const float* x   = (const float*)d_in[0];
    const float* grd = (const float*)d_in[1];
    const float* w   = (const float*)d_in[2];
    const float* sw  = (const float*)d_in[3];
    const float* sb  = (const float*)d_in[4];
    float* out = (float*)d_out;
    float* ws  = (float*)d_ws;

    const size_t need = ((size_t)64 * NCH + 4) * 16384 * 4;  // 512 partials + 4 slices

    if (ws_size >= need) {
        float* part2 = ws + (size_t)64 * NCH * 16384;
        kan_main<<<dim3(64, NCH), 512, 0, stream>>>(x, grd, w, ws, 0);
        kan_reduce<<<dim3(64, 4), 256, 0, stream>>>(ws, part2, 64 * NCH / 4);
        kan_out<<<16, 256, 0, stream>>>(part2, x, sw, sb, out, 4);
    } else {
        hipMemsetAsync(d_out, 0, (size_t)out_size * sizeof(float), stream);
        kan_main<<<dim3(64, NCH), 512, 0, stream>>>(x, grd, w, out, 1);
        kan_out<<<16, 256, 0, stream>>>(nullptr, x, sw, sb, out, 0);
    }
}

// Round 4
// 91.767 us; speedup vs baseline: 2.4390x; 1.2095x over previous
//
#include <hip/hip_runtime.h>
#include <hip/hip_bf16.h>

// B=64, I=64, O=64, G=4096, X=4, RHO=1
#define BB 64
#define II 64
#define OO 64
#define GG 4096
#define KP 32            // g per phase (K per MFMA pass); LDS row = 32 shorts
#define NCH 8            // g-chunks (split-K) -> grid 64 x 8 = 512 blocks
#define GC (GG / NCH)    // 512 g per block
#define NPH (GC / KP)    // 16 phases

typedef short bf16x8 __attribute__((ext_vector_type(8)));
typedef short bf16x4 __attribute__((ext_vector_type(4)));
typedef float f32x4  __attribute__((ext_vector_type(4)));

static __device__ __forceinline__ short f2bf(float f) {
    __hip_bfloat16 h = __float2bfloat16(f);
    return __builtin_bit_cast(short, h);
}

// ---------------------------------------------------------------------------
// Main: bf16 MFMA split-K GEMM, software-pipelined.
//   C[b][(o,x)] += sum_g rbf[b,g] * w[o,g,x]   per block (i, ch) over 512 g.
// 16 phases of K=32; double-buffered LDS (Bs 16KB x2, As 4KB x2 = 40KB);
// ONE barrier per phase: stage p+1 writes buf^1 while MFMA p reads buf
// (safe: MFMA p precedes barrier p+1 per-thread, so stage p+2's overwrite
// of buf[p&1] is behind every thread's MFMA p).
// SWIZZLE (rows are 32 shorts = 64 B): XOR must stay inside the row ->
//   write grp: (k4*4) ^ ((row&3)<<3);  read b128: (lg*8) ^ ((row&3)<<3).
//   Read bank map: quad = (r&1)*4 + (lg ^ (r&3)) -> uniform 8/bank (b128
//   wave64 minimum). r3's (row&7)<<3 overflowed the 32-short row -> garbage.
// ---------------------------------------------------------------------------
__global__ __launch_bounds__(512, 4)
void kan_main(const float* __restrict__ xg, const float* __restrict__ grd,
              const float* __restrict__ wts, float* __restrict__ dst,
              int atomic_mode)
{
    __shared__ __align__(16) unsigned short Bs[2][256 * KP];  // [n][k] 16KB x2
    __shared__ __align__(16) unsigned short As[2][BB * KP];   // [m][k]  4KB x2

    const int i  = blockIdx.x;
    const int ch = blockIdx.y;
    const int g0 = ch * GC;          // float4 index (1 float4 per g)

    const int t    = threadIdx.x;
    const int lane = t & 63;
    const int wv   = t >> 6;
    const int orow = t >> 3;         // o-row for staging == b-row for rbf
    const int gq   = t & 7;          // 4-g chunk within phase

    const float4* wp = reinterpret_cast<const float4*>(wts)
                       + ((size_t)i * OO + orow) * GG + g0 + gq * 4;
    const float4* gp = reinterpret_cast<const float4*>(grd) + g0 + gq * 4;
    const float4  xv = reinterpret_cast<const float4*>(xg)[orow * II + i];

    f32x4 acc[4][2];
    #pragma unroll
    for (int mt = 0; mt < 4; ++mt)
        #pragma unroll
        for (int nt = 0; nt < 2; ++nt) acc[mt][nt] = {0.f, 0.f, 0.f, 0.f};

    // prologue: phase-0 weights
    float4 pre[4];
    #pragma unroll
    for (int q = 0; q < 4; ++q) pre[q] = wp[q];

    for (int p = 0; p < NPH; ++p) {
        unsigned short* Bb = Bs[p & 1];
        unsigned short* Ab = As[p & 1];

        // grid slice loads (L1/L2-resident) — issue early
        float4 gv[4];
        #pragma unroll
        for (int q = 0; q < 4; ++q) gv[q] = gp[p * KP + q];

        // ---- convert weights (waits on pre) + swizzled LDS write ----
        float pf[16];
        #pragma unroll
        for (int q = 0; q < 4; ++q) {
            pf[q * 4 + 0] = pre[q].x; pf[q * 4 + 1] = pre[q].y;
            pf[q * 4 + 2] = pre[q].z; pf[q * 4 + 3] = pre[q].w;
        }
        #pragma unroll
        for (int x = 0; x < 4; ++x) {
            const int n = orow * 4 + x;
            bf16x4 v = {f2bf(pf[0 + x]), f2bf(pf[4 + x]),
                        f2bf(pf[8 + x]), f2bf(pf[12 + x])};
            *reinterpret_cast<bf16x4*>(
                &Bb[n * KP + ((gq * 4) ^ ((n & 3) << 3))]) = v;
        }

        // ---- reissue prefetch immediately (keep HBM queue non-empty) ----
        if (p + 1 < NPH) {
            #pragma unroll
            for (int q = 0; q < 4; ++q) pre[q] = wp[(p + 1) * KP + q];
        }

        // ---- rbf -> bf16, swizzled write ----
        {
            bf16x4 av;
            #pragma unroll
            for (int q = 0; q < 4; ++q) {
                const float d0 = xv.x - gv[q].x, d1 = xv.y - gv[q].y,
                            d2 = xv.z - gv[q].z, d3 = xv.w - gv[q].w;
                av[q] = f2bf(__expf(-(d0 * d0 + d1 * d1 + d2 * d2 + d3 * d3)));
            }
            *reinterpret_cast<bf16x4*>(
                &Ab[orow * KP + ((gq * 4) ^ ((orow & 3) << 3))]) = av;
        }

        __syncthreads();   // buf[p&1] ready; prev MFMA (buf^1) already done

        // ---- MFMA: K=32, 4m x 2n ----
        const int lg  = lane >> 4;        // k-quarter: k = lg*8 + e
        const int r16 = lane & 15;
        bf16x8 af[4], bb[2];
        #pragma unroll
        for (int mt = 0; mt < 4; ++mt) {
            const int r = mt * 16 + r16;
            af[mt] = *reinterpret_cast<const bf16x8*>(
                &As[p & 1][r * KP + ((lg * 8) ^ ((r & 3) << 3))]);
        }
        #pragma unroll
        for (int nt = 0; nt < 2; ++nt) {
            const int r = wv * 32 + nt * 16 + r16;
            bb[nt] = *reinterpret_cast<const bf16x8*>(
                &Bs[p & 1][r * KP + ((lg * 8) ^ ((r & 3) << 3))]);
        }
        #pragma unroll
        for (int mt = 0; mt < 4; ++mt)
            #pragma unroll
            for (int nt = 0; nt < 2; ++nt)
                acc[mt][nt] = __builtin_amdgcn_mfma_f32_16x16x32_bf16(
                    af[mt], bb[nt], acc[mt][nt], 0, 0, 0);
        // no second barrier: next phase writes buf^1, whose last reader
        // (MFMA p-1) is already behind this phase's barrier.
    }

    // ---- epilogue: C/D layout col=lane&15, row=(lane>>4)*4+reg ----
    if (!atomic_mode) {
        float* pp = dst + (size_t)(ch * 64 + i) * (BB * OO * 4);
        #pragma unroll
        for (int mt = 0; mt < 4; ++mt)
            #pragma unroll
            for (int nt = 0; nt < 2; ++nt) {
                const int n  = wv * 32 + nt * 16 + (lane & 15);
                const int mb = mt * 16 + ((lane >> 4) << 2);
                #pragma unroll
                for (int r = 0; r < 4; ++r)
                    pp[(mb + r) * 256 + n] = acc[mt][nt][r];
            }
    } else {
        #pragma unroll
        for (int mt = 0; mt < 4; ++mt)
            #pragma unroll
            for (int nt = 0; nt < 2; ++nt) {
                const int n  = wv * 32 + nt * 16 + (lane & 15);
                const int mb = mt * 16 + ((lane >> 4) << 2);
                #pragma unroll
                for (int r = 0; r < 4; ++r)
                    atomicAdd(&dst[(mb + r) * 256 + n], acc[mt][nt][r]);
            }
    }
}

// ---------------------------------------------------------------------------
// Tree-reduce 512 partials -> 4 slices
// ---------------------------------------------------------------------------
__global__ void kan_reduce(const float* __restrict__ part,
                           float* __restrict__ part2, int Q)
{
    const int idx = blockIdx.x * 256 + threadIdx.x;  // [0, 16384)
    const int pg  = blockIdx.y;                      // [0, 4)
    const float* p = part + (size_t)pg * Q * 16384 + idx;
    float s = 0.f;
    #pragma unroll 8
    for (int q = 0; q < Q; ++q) s += p[(size_t)q * 16384];
    part2[pg * 16384 + idx] = s;
}

// ---------------------------------------------------------------------------
// Final sum + SiLU/Cayley (Cl(2,0), static signs) + bias
// ---------------------------------------------------------------------------
__global__ void kan_out(const float* __restrict__ part2,
                        const float* __restrict__ xg,
                        const float* __restrict__ sw,
                        const float* __restrict__ sb,
                        float* __restrict__ out, int R)
{
    const int t = blockIdx.x * 256 + threadIdx.x;    // (b,o)
    const int b = t >> 6, o = t & 63;

    float o0, o1, o2, o3;
    if (R > 0) {
        o0 = o1 = o2 = o3 = 0.f;
        const float4* p2 = reinterpret_cast<const float4*>(part2);
        for (int r = 0; r < R; ++r) {
            const float4 v = p2[(size_t)r * 4096 + t];
            o0 += v.x; o1 += v.y; o2 += v.z; o3 += v.w;
        }
    } else {
        const float4 v = reinterpret_cast<const float4*>(out)[t];
        o0 = v.x; o1 = v.y; o2 = v.z; o3 = v.w;
    }

    const float4* xg4 = reinterpret_cast<const float4*>(xg);
    const float4* sw4 = reinterpret_cast<const float4*>(sw);
    const float4* sb4 = reinterpret_cast<const float4*>(sb);
    #pragma unroll 4
    for (int i = 0; i < II; ++i) {
        const float4 xvv = xg4[b * II + i];
        const float4 swv = sw4[i * OO + o];
        const float4 sbv = sb4[i * OO + o];
        const float s0 = xvv.x / (1.f + __expf(-xvv.x));
        const float s1 = xvv.y / (1.f + __expf(-xvv.y));
        const float s2 = xvv.z / (1.f + __expf(-xvv.z));
        const float s3 = xvv.w / (1.f + __expf(-xvv.w));
        o0 += swv.x * s0 + swv.y * s1 + swv.z * s2 - swv.w * s3 + sbv.x;
        o1 += swv.x * s1 + swv.y * s0 - swv.z * s3 + swv.w * s2 + sbv.y;
        o2 += swv.x * s2 + swv.y * s3 + swv.z * s0 - swv.w * s1 + sbv.z;
        o3 += swv.x * s3 + swv.y * s2 - swv.z * s1 + swv.w * s0 + sbv.w;
    }
    reinterpret_cast<float4*>(out)[t] = make_float4(o0, o1, o2, o3);
}

// ---------------------------------------------------------------------------
extern "C" void kernel_launch(void* const* d_in, const int* in_sizes, int n_in,
                              void* d_out, int out_size, void* d_ws, size_t ws_size,
                              hipStream_t stream)
{
    const float* x   = (const float*)d_in[0];
    const float* grd = (const float*)d_in[1];
    const float* w   = (const float*)d_in[2];
    const float* sw  = (const float*)d_in[3];
    const float* sb  = (const float*)d_in[4];
    float* out = (float*)d_out;
    float* ws  = (float*)d_ws;

    const size_t need = ((size_t)64 * NCH + 4) * 16384 * 4;  // 512 partials + 4 slices

    if (ws_size >= need) {
        float* part2 = ws + (size_t)64 * NCH * 16384;
        kan_main<<<dim3(64, NCH), 512, 0, stream>>>(x, grd, w, ws, 0);
        kan_reduce<<<dim3(64, 4), 256, 0, stream>>>(ws, part2, 64 * NCH / 4);
        kan_out<<<16, 256, 0, stream>>>(part2, x, sw, sb, out, 4);
    } else {
        hipMemsetAsync(d_out, 0, (size_t)out_size * sizeof(float), stream);
        kan_main<<<dim3(64, NCH), 512, 0, stream>>>(x, grd, w, out, 1);
        kan_out<<<16, 256, 0, stream>>>(nullptr, x, sw, sb, out, 0);
    }
}

// Round 5
// 90.903 us; speedup vs baseline: 2.4623x; 1.0095x over previous
//
#include <hip/hip_runtime.h>
#include <hip/hip_bf16.h>

// B=64, I=64, O=64, G=4096, X=4, RHO=1
#define BB 64
#define II 64
#define OO 64
#define GG 4096
#define KP 32            // g per phase (K per MFMA pass); LDS row = 32 shorts
#define NCH 8            // g-chunks (split-K) -> grid 64 x 8 = 512 blocks
#define GC (GG / NCH)    // 512 g per block
#define NPH (GC / KP)    // 16 phases

typedef short bf16x8 __attribute__((ext_vector_type(8)));
typedef short bf16x4 __attribute__((ext_vector_type(4)));
typedef float f32x4  __attribute__((ext_vector_type(4)));

static __device__ __forceinline__ short f2bf(float f) {
    __hip_bfloat16 h = __float2bfloat16(f);
    return __builtin_bit_cast(short, h);
}

// Raw barrier with LDS-only drain (T4): ds_writes must be visible across the
// barrier (lgkmcnt(0)), but outstanding GLOBAL loads (next-phase prefetch)
// deliberately stay in flight -- __syncthreads() would emit a full
// s_waitcnt vmcnt(0) drain [m97] and idle HBM during every MFMA window.
static __device__ __forceinline__ void lds_barrier() {
    asm volatile("s_waitcnt lgkmcnt(0)" ::: "memory");
    __builtin_amdgcn_s_barrier();
}

// ---------------------------------------------------------------------------
// Main: bf16 MFMA split-K GEMM, software-pipelined.
//   C[b][(o,x)] += sum_g rbf[b,g] * w[o,g,x]   per block (i, ch) over 512 g.
// 16 phases of K=32; double-buffered LDS (Bs 16KB x2, As 4KB x2 = 40KB);
// ONE lds_barrier per phase: stage p+1 writes buf^1 while MFMA p reads buf.
// Cross-phase safety: wave's MFMA-p ds_reads are drained by its own
// lgkmcnt(0) before barrier p+1, and stage p+2 (same buffer) starts only
// after barrier p+1 -> no overwrite race.
// SWIZZLE (rows are 32 shorts = 64 B): XOR stays inside the row:
//   write grp: (gq*4) ^ ((row&3)<<3);  read b128: (lg*8) ^ ((row&3)<<3).
// ---------------------------------------------------------------------------
__global__ __launch_bounds__(512, 4)
void kan_main(const float* __restrict__ xg, const float* __restrict__ grd,
              const float* __restrict__ wts, float* __restrict__ dst,
              int atomic_mode)
{
    __shared__ __align__(16) unsigned short Bs[2][256 * KP];  // [n][k] 16KB x2
    __shared__ __align__(16) unsigned short As[2][BB * KP];   // [m][k]  4KB x2

    const int i  = blockIdx.x;
    const int ch = blockIdx.y;
    const int g0 = ch * GC;          // float4 index (1 float4 per g)

    const int t    = threadIdx.x;
    const int lane = t & 63;
    const int wv   = t >> 6;
    const int orow = t >> 3;         // o-row for staging == b-row for rbf
    const int gq   = t & 7;          // 4-g chunk within phase

    const float4* wp = reinterpret_cast<const float4*>(wts)
                       + ((size_t)i * OO + orow) * GG + g0 + gq * 4;
    const float4* gp = reinterpret_cast<const float4*>(grd) + g0 + gq * 4;
    const float4  xv = reinterpret_cast<const float4*>(xg)[orow * II + i];

    f32x4 acc[4][2];
    #pragma unroll
    for (int mt = 0; mt < 4; ++mt)
        #pragma unroll
        for (int nt = 0; nt < 2; ++nt) acc[mt][nt] = {0.f, 0.f, 0.f, 0.f};

    // prologue: phase-0 weights
    float4 pre[4];
    #pragma unroll
    for (int q = 0; q < 4; ++q) pre[q] = wp[q];

    for (int p = 0; p < NPH; ++p) {
        unsigned short* Bb = Bs[p & 1];
        unsigned short* Ab = As[p & 1];

        // grid slice loads (L1/L2-resident) — issue early
        float4 gv[4];
        #pragma unroll
        for (int q = 0; q < 4; ++q) gv[q] = gp[p * KP + q];

        // ---- convert weights (counted-vmcnt wait on pre) + LDS write ----
        float pf[16];
        #pragma unroll
        for (int q = 0; q < 4; ++q) {
            pf[q * 4 + 0] = pre[q].x; pf[q * 4 + 1] = pre[q].y;
            pf[q * 4 + 2] = pre[q].z; pf[q * 4 + 3] = pre[q].w;
        }
        #pragma unroll
        for (int x = 0; x < 4; ++x) {
            const int n = orow * 4 + x;
            bf16x4 v = {f2bf(pf[0 + x]), f2bf(pf[4 + x]),
                        f2bf(pf[8 + x]), f2bf(pf[12 + x])};
            *reinterpret_cast<bf16x4*>(
                &Bb[n * KP + ((gq * 4) ^ ((n & 3) << 3))]) = v;
        }

        // ---- reissue prefetch immediately (stays in flight across the
        //      barrier; consumed by next phase's convert) ----
        if (p + 1 < NPH) {
            #pragma unroll
            for (int q = 0; q < 4; ++q) pre[q] = wp[(p + 1) * KP + q];
        }

        // ---- rbf -> bf16, swizzled write ----
        {
            bf16x4 av;
            #pragma unroll
            for (int q = 0; q < 4; ++q) {
                const float d0 = xv.x - gv[q].x, d1 = xv.y - gv[q].y,
                            d2 = xv.z - gv[q].z, d3 = xv.w - gv[q].w;
                av[q] = f2bf(__expf(-(d0 * d0 + d1 * d1 + d2 * d2 + d3 * d3)));
            }
            *reinterpret_cast<bf16x4*>(
                &Ab[orow * KP + ((gq * 4) ^ ((orow & 3) << 3))]) = av;
        }

        lds_barrier();   // buf[p&1] ready; global prefetch NOT drained

        // ---- MFMA: K=32, 4m x 2n ----
        const int lg  = lane >> 4;        // k-quarter: k = lg*8 + e
        const int r16 = lane & 15;
        bf16x8 af[4], bb[2];
        #pragma unroll
        for (int mt = 0; mt < 4; ++mt) {
            const int r = mt * 16 + r16;
            af[mt] = *reinterpret_cast<const bf16x8*>(
                &As[p & 1][r * KP + ((lg * 8) ^ ((r & 3) << 3))]);
        }
        #pragma unroll
        for (int nt = 0; nt < 2; ++nt) {
            const int r = wv * 32 + nt * 16 + r16;
            bb[nt] = *reinterpret_cast<const bf16x8*>(
                &Bs[p & 1][r * KP + ((lg * 8) ^ ((r & 3) << 3))]);
        }
        #pragma unroll
        for (int mt = 0; mt < 4; ++mt)
            #pragma unroll
            for (int nt = 0; nt < 2; ++nt)
                acc[mt][nt] = __builtin_amdgcn_mfma_f32_16x16x32_bf16(
                    af[mt], bb[nt], acc[mt][nt], 0, 0, 0);
        // no second barrier: next phase writes buf^1, whose last reader
        // (MFMA p-1) is already behind this phase's barrier.
    }

    // ---- epilogue: C/D layout col=lane&15, row=(lane>>4)*4+reg ----
    if (!atomic_mode) {
        float* pp = dst + (size_t)(ch * 64 + i) * (BB * OO * 4);
        #pragma unroll
        for (int mt = 0; mt < 4; ++mt)
            #pragma unroll
            for (int nt = 0; nt < 2; ++nt) {
                const int n  = wv * 32 + nt * 16 + (lane & 15);
                const int mb = mt * 16 + ((lane >> 4) << 2);
                #pragma unroll
                for (int r = 0; r < 4; ++r)
                    pp[(mb + r) * 256 + n] = acc[mt][nt][r];
            }
    } else {
        #pragma unroll
        for (int mt = 0; mt < 4; ++mt)
            #pragma unroll
            for (int nt = 0; nt < 2; ++nt) {
                const int n  = wv * 32 + nt * 16 + (lane & 15);
                const int mb = mt * 16 + ((lane >> 4) << 2);
                #pragma unroll
                for (int r = 0; r < 4; ++r)
                    atomicAdd(&dst[(mb + r) * 256 + n], acc[mt][nt][r]);
            }
    }
}

// ---------------------------------------------------------------------------
// Tree-reduce 512 partials -> 4 slices
// ---------------------------------------------------------------------------
__global__ void kan_reduce(const float* __restrict__ part,
                           float* __restrict__ part2, int Q)
{
    const int idx = blockIdx.x * 256 + threadIdx.x;  // [0, 16384)
    const int pg  = blockIdx.y;                      // [0, 4)
    const float* p = part + (size_t)pg * Q * 16384 + idx;
    float s = 0.f;
    #pragma unroll 8
    for (int q = 0; q < Q; ++q) s += p[(size_t)q * 16384];
    part2[pg * 16384 + idx] = s;
}

// ---------------------------------------------------------------------------
// Final sum + SiLU/Cayley (Cl(2,0), static signs) + bias
// ---------------------------------------------------------------------------
__global__ void kan_out(const float* __restrict__ part2,
                        const float* __restrict__ xg,
                        const float* __restrict__ sw,
                        const float* __restrict__ sb,
                        float* __restrict__ out, int R)
{
    const int t = blockIdx.x * 256 + threadIdx.x;    // (b,o)
    const int b = t >> 6, o = t & 63;

    float o0, o1, o2, o3;
    if (R > 0) {
        o0 = o1 = o2 = o3 = 0.f;
        const float4* p2 = reinterpret_cast<const float4*>(part2);
        for (int r = 0; r < R; ++r) {
            const float4 v = p2[(size_t)r * 4096 + t];
            o0 += v.x; o1 += v.y; o2 += v.z; o3 += v.w;
        }
    } else {
        const float4 v = reinterpret_cast<const float4*>(out)[t];
        o0 = v.x; o1 = v.y; o2 = v.z; o3 = v.w;
    }

    const float4* xg4 = reinterpret_cast<const float4*>(xg);
    const float4* sw4 = reinterpret_cast<const float4*>(sw);
    const float4* sb4 = reinterpret_cast<const float4*>(sb);
    #pragma unroll 4
    for (int i = 0; i < II; ++i) {
        const float4 xvv = xg4[b * II + i];
        const float4 swv = sw4[i * OO + o];
        const float4 sbv = sb4[i * OO + o];
        const float s0 = xvv.x / (1.f + __expf(-xvv.x));
        const float s1 = xvv.y / (1.f + __expf(-xvv.y));
        const float s2 = xvv.z / (1.f + __expf(-xvv.z));
        const float s3 = xvv.w / (1.f + __expf(-xvv.w));
        o0 += swv.x * s0 + swv.y * s1 + swv.z * s2 - swv.w * s3 + sbv.x;
        o1 += swv.x * s1 + swv.y * s0 - swv.z * s3 + swv.w * s2 + sbv.y;
        o2 += swv.x * s2 + swv.y * s3 + swv.z * s0 - swv.w * s1 + sbv.z;
        o3 += swv.x * s3 + swv.y * s2 - swv.z * s1 + swv.w * s0 + sbv.w;
    }
    reinterpret_cast<float4*>(out)[t] = make_float4(o0, o1, o2, o3);
}

// ---------------------------------------------------------------------------
extern "C" void kernel_launch(void* const* d_in, const int* in_sizes, int n_in,
                              void* d_out, int out_size, void* d_ws, size_t ws_size,
                              hipStream_t stream)
{
    const float* x   = (const float*)d_in[0];
    const float* grd = (const float*)d_in[1];
    const float* w   = (const float*)d_in[2];
    const float* sw  = (const float*)d_in[3];
    const float* sb  = (const float*)d_in[4];
    float* out = (float*)d_out;
    float* ws  = (float*)d_ws;

    const size_t need = ((size_t)64 * NCH + 4) * 16384 * 4;  // 512 partials + 4 slices

    if (ws_size >= need) {
        float* part2 = ws + (size_t)64 * NCH * 16384;
        kan_main<<<dim3(64, NCH), 512, 0, stream>>>(x, grd, w, ws, 0);
        kan_reduce<<<dim3(64, 4), 256, 0, stream>>>(ws, part2, 64 * NCH / 4);
        kan_out<<<16, 256, 0, stream>>>(part2, x, sw, sb, out, 4);
    } else {
        hipMemsetAsync(d_out, 0, (size_t)out_size * sizeof(float), stream);
        kan_main<<<dim3(64, NCH), 512, 0, stream>>>(x, grd, w, out, 1);
        kan_out<<<16, 256, 0, stream>>>(nullptr, x, sw, sb, out, 0);
    }
}

// Round 6
// 85.762 us; speedup vs baseline: 2.6098x; 1.0599x over previous
//
#include <hip/hip_runtime.h>
#include <hip/hip_bf16.h>

// B=64, I=64, O=64, G=4096, X=4, RHO=1
#define BB 64
#define II 64
#define OO 64
#define GG 4096
#define KP 32            // g per phase (K per MFMA pass); LDS row = 32 shorts
#define NCH 8            // g-chunks (split-K) -> grid 64 x 8 = 512 blocks
#define GC (GG / NCH)    // 512 g per block
#define NPH (GC / KP)    // 16 phases

typedef short bf16x8 __attribute__((ext_vector_type(8)));
typedef short bf16x4 __attribute__((ext_vector_type(4)));
typedef float f32x4  __attribute__((ext_vector_type(4)));

static __device__ __forceinline__ short f2bf(float f) {
    __hip_bfloat16 h = __float2bfloat16(f);
    return __builtin_bit_cast(short, h);
}

// Raw barrier with LDS-only drain: ds ops visible across the barrier, global
// prefetch loads deliberately stay in flight (counted vmcnt at consumer).
static __device__ __forceinline__ void lds_barrier() {
    asm volatile("s_waitcnt lgkmcnt(0)" ::: "memory");
    __builtin_amdgcn_s_barrier();
}

// ---------------------------------------------------------------------------
// Main: bf16 MFMA split-K GEMM, software-pipelined.
//   C[b][(o,x)] += sum_g rbf[b,g] * w[o,g,x]   per block (i, ch) over 512 g.
// 16 phases of K=32; double-buffered LDS; ONE lds_barrier per phase.
//
// WEIGHT STAGING (r6 change): lane-contiguous loads. Load q of thread t
// fetches float4 (row = q*16 + (t>>5), col c = t&31) of the phase's [64][32]
// float4 tile -> within one instruction, each 32-lane half covers 512 B
// CONTIGUOUS (one request per 64 B line), vs r5's 16 B requests at stride
// 64 B (4 instructions per line -> ~2x request inflation, ~50% eff. BW).
// Each float4 is the 4 x-components of one (o,g): LDS write = 4 ds_write_b16
// per load at column c ^ (x<<3)  (== k ^ ((n&3)<<3), matching the b128 read
// swizzle since n = 4*row + x -> n&3 = x). Write bank map: 16 banks, 4-way
// (1.58x per m136) on a term that is ~5% of the phase budget.
// ---------------------------------------------------------------------------
__global__ __launch_bounds__(512, 4)
void kan_main(const float* __restrict__ xg, const float* __restrict__ grd,
              const float* __restrict__ wts, float* __restrict__ dst,
              int atomic_mode)
{
    __shared__ __align__(16) unsigned short Bs[2][256 * KP];  // [n][k] 16KB x2
    __shared__ __align__(16) unsigned short As[2][BB * KP];   // [m][k]  4KB x2

    const int i  = blockIdx.x;
    const int ch = blockIdx.y;
    const int g0 = ch * GC;          // float4 index (1 float4 per g)

    const int t    = threadIdx.x;
    const int lane = t & 63;
    const int wv   = t >> 6;

    // weight staging map (lane-contiguous)
    const int c  = t & 31;           // g-col within phase
    const int r0 = t >> 5;           // row base (0..15); rows r0 + 16q
    const float4* wrow = reinterpret_cast<const float4*>(wts)
                         + (size_t)i * OO * GG + g0 + c;

    // rbf task map (unchanged)
    const int orow = t >> 3;         // b-row
    const int gq   = t & 7;          // 4-g chunk within phase
    const float4* gp = reinterpret_cast<const float4*>(grd) + g0 + gq * 4;
    const float4  xv = reinterpret_cast<const float4*>(xg)[orow * II + i];

    f32x4 acc[4][2];
    #pragma unroll
    for (int mt = 0; mt < 4; ++mt)
        #pragma unroll
        for (int nt = 0; nt < 2; ++nt) acc[mt][nt] = {0.f, 0.f, 0.f, 0.f};

    // prologue: phase-0 weights
    float4 pre[4];
    #pragma unroll
    for (int q = 0; q < 4; ++q)
        pre[q] = wrow[(size_t)(q * 16 + r0) * GG];

    for (int p = 0; p < NPH; ++p) {
        unsigned short* Bb = Bs[p & 1];
        unsigned short* Ab = As[p & 1];

        // grid slice loads (L1-broadcast, 512 B unique/phase) — issue early
        float4 gv[4];
        #pragma unroll
        for (int q = 0; q < 4; ++q) gv[q] = gp[p * KP + q];

        // ---- convert weights + swizzled LDS write; reissue load q ASAP ----
        #pragma unroll
        for (int q = 0; q < 4; ++q) {
            const int   row = q * 16 + r0;
            const float4 w4 = pre[q];                 // counted-vmcnt wait
            if (p + 1 < NPH)
                pre[q] = wrow[(size_t)row * GG + (p + 1) * KP];
            unsigned short* bp = &Bb[(row * 4) * KP];
            bp[0 * KP + (c     )] = (unsigned short)f2bf(w4.x);
            bp[1 * KP + (c ^  8)] = (unsigned short)f2bf(w4.y);
            bp[2 * KP + (c ^ 16)] = (unsigned short)f2bf(w4.z);
            bp[3 * KP + (c ^ 24)] = (unsigned short)f2bf(w4.w);
        }

        // ---- rbf -> bf16, swizzled write ----
        {
            bf16x4 av;
            #pragma unroll
            for (int q = 0; q < 4; ++q) {
                const float d0 = xv.x - gv[q].x, d1 = xv.y - gv[q].y,
                            d2 = xv.z - gv[q].z, d3 = xv.w - gv[q].w;
                av[q] = f2bf(__expf(-(d0 * d0 + d1 * d1 + d2 * d2 + d3 * d3)));
            }
            *reinterpret_cast<bf16x4*>(
                &Ab[orow * KP + ((gq * 4) ^ ((orow & 3) << 3))]) = av;
        }

        lds_barrier();   // buf[p&1] ready; global prefetch NOT drained

        // ---- MFMA: K=32, 4m x 2n ----
        const int lg  = lane >> 4;        // k-quarter: k = lg*8 + e
        const int r16 = lane & 15;
        bf16x8 af[4], bb[2];
        #pragma unroll
        for (int mt = 0; mt < 4; ++mt) {
            const int r = mt * 16 + r16;
            af[mt] = *reinterpret_cast<const bf16x8*>(
                &As[p & 1][r * KP + ((lg * 8) ^ ((r & 3) << 3))]);
        }
        #pragma unroll
        for (int nt = 0; nt < 2; ++nt) {
            const int r = wv * 32 + nt * 16 + r16;
            bb[nt] = *reinterpret_cast<const bf16x8*>(
                &Bs[p & 1][r * KP + ((lg * 8) ^ ((r & 3) << 3))]);
        }
        #pragma unroll
        for (int mt = 0; mt < 4; ++mt)
            #pragma unroll
            for (int nt = 0; nt < 2; ++nt)
                acc[mt][nt] = __builtin_amdgcn_mfma_f32_16x16x32_bf16(
                    af[mt], bb[nt], acc[mt][nt], 0, 0, 0);
        // no second barrier: next phase writes buf^1, whose last reader
        // (MFMA p-1) is already behind this phase's barrier.
    }

    // ---- epilogue: C/D layout col=lane&15, row=(lane>>4)*4+reg ----
    if (!atomic_mode) {
        float* pp = dst + (size_t)(ch * 64 + i) * (BB * OO * 4);
        #pragma unroll
        for (int mt = 0; mt < 4; ++mt)
            #pragma unroll
            for (int nt = 0; nt < 2; ++nt) {
                const int n  = wv * 32 + nt * 16 + (lane & 15);
                const int mb = mt * 16 + ((lane >> 4) << 2);
                #pragma unroll
                for (int r = 0; r < 4; ++r)
                    pp[(mb + r) * 256 + n] = acc[mt][nt][r];
            }
    } else {
        #pragma unroll
        for (int mt = 0; mt < 4; ++mt)
            #pragma unroll
            for (int nt = 0; nt < 2; ++nt) {
                const int n  = wv * 32 + nt * 16 + (lane & 15);
                const int mb = mt * 16 + ((lane >> 4) << 2);
                #pragma unroll
                for (int r = 0; r < 4; ++r)
                    atomicAdd(&dst[(mb + r) * 256 + n], acc[mt][nt][r]);
            }
    }
}

// ---------------------------------------------------------------------------
// Tree-reduce 512 partials -> 4 slices
// ---------------------------------------------------------------------------
__global__ void kan_reduce(const float* __restrict__ part,
                           float* __restrict__ part2, int Q)
{
    const int idx = blockIdx.x * 256 + threadIdx.x;  // [0, 16384)
    const int pg  = blockIdx.y;                      // [0, 4)
    const float* p = part + (size_t)pg * Q * 16384 + idx;
    float s = 0.f;
    #pragma unroll 8
    for (int q = 0; q < Q; ++q) s += p[(size_t)q * 16384];
    part2[pg * 16384 + idx] = s;
}

// ---------------------------------------------------------------------------
// Final sum + SiLU/Cayley (Cl(2,0), static signs) + bias
// ---------------------------------------------------------------------------
__global__ void kan_out(const float* __restrict__ part2,
                        const float* __restrict__ xg,
                        const float* __restrict__ sw,
                        const float* __restrict__ sb,
                        float* __restrict__ out, int R)
{
    const int t = blockIdx.x * 256 + threadIdx.x;    // (b,o)
    const int b = t >> 6, o = t & 63;

    float o0, o1, o2, o3;
    if (R > 0) {
        o0 = o1 = o2 = o3 = 0.f;
        const float4* p2 = reinterpret_cast<const float4*>(part2);
        for (int r = 0; r < R; ++r) {
            const float4 v = p2[(size_t)r * 4096 + t];
            o0 += v.x; o1 += v.y; o2 += v.z; o3 += v.w;
        }
    } else {
        const float4 v = reinterpret_cast<const float4*>(out)[t];
        o0 = v.x; o1 = v.y; o2 = v.z; o3 = v.w;
    }

    const float4* xg4 = reinterpret_cast<const float4*>(xg);
    const float4* sw4 = reinterpret_cast<const float4*>(sw);
    const float4* sb4 = reinterpret_cast<const float4*>(sb);
    #pragma unroll 4
    for (int i = 0; i < II; ++i) {
        const float4 xvv = xg4[b * II + i];
        const float4 swv = sw4[i * OO + o];
        const float4 sbv = sb4[i * OO + o];
        const float s0 = xvv.x / (1.f + __expf(-xvv.x));
        const float s1 = xvv.y / (1.f + __expf(-xvv.y));
        const float s2 = xvv.z / (1.f + __expf(-xvv.z));
        const float s3 = xvv.w / (1.f + __expf(-xvv.w));
        o0 += swv.x * s0 + swv.y * s1 + swv.z * s2 - swv.w * s3 + sbv.x;
        o1 += swv.x * s1 + swv.y * s0 - swv.z * s3 + swv.w * s2 + sbv.y;
        o2 += swv.x * s2 + swv.y * s3 + swv.z * s0 - swv.w * s1 + sbv.z;
        o3 += swv.x * s3 + swv.y * s2 - swv.z * s1 + swv.w * s0 + sbv.w;
    }
    reinterpret_cast<float4*>(out)[t] = make_float4(o0, o1, o2, o3);
}

// ---------------------------------------------------------------------------
extern "C" void kernel_launch(void* const* d_in, const int* in_sizes, int n_in,
                              void* d_out, int out_size, void* d_ws, size_t ws_size,
                              hipStream_t stream)
{
    const float* x   = (const float*)d_in[0];
    const float* grd = (const float*)d_in[1];
    const float* w   = (const float*)d_in[2];
    const float* sw  = (const float*)d_in[3];
    const float* sb  = (const float*)d_in[4];
    float* out = (float*)d_out;
    float* ws  = (float*)d_ws;

    const size_t need = ((size_t)64 * NCH + 4) * 16384 * 4;  // 512 partials + 4 slices

    if (ws_size >= need) {
        float* part2 = ws + (size_t)64 * NCH * 16384;
        kan_main<<<dim3(64, NCH), 512, 0, stream>>>(x, grd, w, ws, 0);
        kan_reduce<<<dim3(64, 4), 256, 0, stream>>>(ws, part2, 64 * NCH / 4);
        kan_out<<<16, 256, 0, stream>>>(part2, x, sw, sb, out, 4);
    } else {
        hipMemsetAsync(d_out, 0, (size_t)out_size * sizeof(float), stream);
        kan_main<<<dim3(64, NCH), 512, 0, stream>>>(x, grd, w, out, 1);
        kan_out<<<16, 256, 0, stream>>>(nullptr, x, sw, sb, out, 0);
    }
}